// Round 1
// baseline (2169.518 us; speedup 1.0000x reference)
//
#include <hip/hip_runtime.h>

// Problem constants (from reference): N=50000, E=600000, F=128, H=128, O=64, R=8
#define F_DIM 128
#define H_DIM 128
#define O_DIM 64
#define R_NUM 8

// ---------------- min/max of edge weights (non-negative -> int-punned atomics) ----
__global__ void init_mm(float* mm) {
    if (threadIdx.x == 0) {
        ((int*)mm)[0] = 0x7f800000;  // +inf
        ((int*)mm)[1] = 0x00000000;  // 0.0f
    }
}

__global__ void minmax_kernel(const float* __restrict__ w, int E, float* mm) {
    __shared__ float smn[256], smx[256];
    int tid = threadIdx.x;
    float mn = 1e30f, mx = -1e30f;
    for (int i = blockIdx.x * blockDim.x + tid; i < E; i += gridDim.x * blockDim.x) {
        float v = w[i];
        mn = fminf(mn, v);
        mx = fmaxf(mx, v);
    }
    smn[tid] = mn; smx[tid] = mx;
    __syncthreads();
    for (int s = 128; s > 0; s >>= 1) {
        if (tid < s) {
            smn[tid] = fminf(smn[tid], smn[tid + s]);
            smx[tid] = fmaxf(smx[tid], smx[tid + s]);
        }
        __syncthreads();
    }
    if (tid == 0) {
        atomicMin((int*)mm + 0, __float_as_int(smn[0]));
        atomicMax((int*)mm + 1, __float_as_int(smx[0]));
    }
}

__global__ void norm_kernel(const float* __restrict__ w, float* __restrict__ ewn,
                            const float* __restrict__ mm, int E) {
    int i = blockIdx.x * blockDim.x + threadIdx.x;
    if (i < E) {
        float mn = mm[0], mx = mm[1];
        ewn[i] = (w[i] - mn) / (mx - mn + 1e-8f);
    }
}

// ---------------- degree count + inverse --------------------------------------
__global__ void count_kernel(const int* __restrict__ dst, float* __restrict__ cnt, int E) {
    int i = blockIdx.x * blockDim.x + threadIdx.x;
    if (i < E) atomicAdd(&cnt[dst[i]], 1.0f);
}

__global__ void invert_kernel(float* __restrict__ cnt, int N) {
    int i = blockIdx.x * blockDim.x + threadIdx.x;
    if (i < N) cnt[i] = 1.0f / fmaxf(cnt[i], 1.0f);
}

// ---------------- fp32 tiled GEMM: C[MxNcol] = A[MxK] @ B[KxNcol] --------------
// BM=BN=64, BK=16, 256 threads, 4x4 per thread. K must be /16, Ncol /64.
__global__ __launch_bounds__(256) void gemm_nn(const float* __restrict__ A,
                                               const float* __restrict__ B,
                                               float* __restrict__ C,
                                               int M, int K, int Ncol) {
    __shared__ float As[16][64];   // [k][m]
    __shared__ float Bs[16][64];   // [k][n]
    const int tid = threadIdx.x;
    const int bm = blockIdx.x * 64;
    const int bn = blockIdx.y * 64;
    const int tx = tid & 15;   // 0..15 -> cols
    const int ty = tid >> 4;   // 0..15 -> rows
    const int ar = tid >> 2;          // 0..63 row within A tile
    const int ac = (tid & 3) << 2;    // 0,4,8,12 k-offset
    const int br = tid >> 4;          // 0..15 k row of B tile
    const int bc = (tid & 15) << 2;   // col offset
    int arow = bm + ar;
    if (arow >= M) arow = M - 1;      // clamp; stores are guarded

    float acc[4][4] = {};
    for (int k0 = 0; k0 < K; k0 += 16) {
        float4 av = *(const float4*)(A + (size_t)arow * K + k0 + ac);
        float4 bv = *(const float4*)(B + (size_t)(k0 + br) * Ncol + bn + bc);
        As[ac + 0][ar] = av.x; As[ac + 1][ar] = av.y;
        As[ac + 2][ar] = av.z; As[ac + 3][ar] = av.w;
        Bs[br][bc + 0] = bv.x; Bs[br][bc + 1] = bv.y;
        Bs[br][bc + 2] = bv.z; Bs[br][bc + 3] = bv.w;
        __syncthreads();
#pragma unroll
        for (int kk = 0; kk < 16; ++kk) {
            float a[4], b[4];
#pragma unroll
            for (int i = 0; i < 4; ++i) a[i] = As[kk][ty * 4 + i];
#pragma unroll
            for (int j = 0; j < 4; ++j) b[j] = Bs[kk][tx * 4 + j];
#pragma unroll
            for (int i = 0; i < 4; ++i)
#pragma unroll
                for (int j = 0; j < 4; ++j)
                    acc[i][j] += a[i] * b[j];
        }
        __syncthreads();
    }
#pragma unroll
    for (int i = 0; i < 4; ++i) {
        int row = bm + ty * 4 + i;
        if (row < M) {
            float4 o = make_float4(acc[i][0], acc[i][1], acc[i][2], acc[i][3]);
            *(float4*)(C + (size_t)row * Ncol + bn + tx * 4) = o;
        }
    }
}

// ---------------- scatter: agg[dst] += ew * proj[src] for edges of type rel ----
template <int CH>
__global__ void scatter_rel(const int* __restrict__ src, const int* __restrict__ dst,
                            const int* __restrict__ et, const float* __restrict__ ewn,
                            const float* __restrict__ proj, float* __restrict__ agg,
                            int E, int rel) {
    constexpr int LPE = CH / 4;  // lanes per edge (32 for 128, 16 for 64)
    int gid = blockIdx.x * blockDim.x + threadIdx.x;
    int e = gid / LPE;
    if (e >= E) return;
    if (et[e] != rel) return;
    int j = (gid % LPE) * 4;
    float w = ewn[e];
    int s = src[e], d = dst[e];
    float4 v = *(const float4*)(proj + (size_t)s * CH + j);
    float* out = agg + (size_t)d * CH + j;
    atomicAdd(out + 0, v.x * w);
    atomicAdd(out + 1, v.y * w);
    atomicAdd(out + 2, v.z * w);
    atomicAdd(out + 3, v.w * w);
}

// ---------------- finalize: out = agg*inv_cnt + xr + bias (opt relu) -----------
template <int CH, bool RELU>
__global__ void finalize_kernel(const float* __restrict__ agg, const float* __restrict__ xr,
                                const float* __restrict__ bias, const float* __restrict__ invc,
                                float* __restrict__ out, int N) {
    constexpr int LPE = CH / 4;
    int gid = blockIdx.x * blockDim.x + threadIdx.x;
    int n = gid / LPE;
    if (n >= N) return;
    int j = (gid % LPE) * 4;
    float inv = invc[n];
    float4 a = *(const float4*)(agg + (size_t)n * CH + j);
    float4 x = *(const float4*)(xr + (size_t)n * CH + j);
    float4 b = *(const float4*)(bias + j);
    float4 o;
    o.x = a.x * inv + x.x + b.x;
    o.y = a.y * inv + x.y + b.y;
    o.z = a.z * inv + x.z + b.z;
    o.w = a.w * inv + x.w + b.w;
    if (RELU) {
        o.x = fmaxf(o.x, 0.0f); o.y = fmaxf(o.y, 0.0f);
        o.z = fmaxf(o.z, 0.0f); o.w = fmaxf(o.w, 0.0f);
    }
    *(float4*)(out + (size_t)n * CH + j) = o;
}

extern "C" void kernel_launch(void* const* d_in, const int* in_sizes, int n_in,
                              void* d_out, int out_size, void* d_ws, size_t ws_size,
                              hipStream_t stream) {
    const float* x     = (const float*)d_in[0];
    const int*   ei    = (const int*)d_in[1];
    const float* ew    = (const float*)d_in[2];
    const int*   et    = (const int*)d_in[3];
    const float* W1    = (const float*)d_in[4];
    const float* root1 = (const float*)d_in[5];
    const float* bias1 = (const float*)d_in[6];
    const float* W2    = (const float*)d_in[7];
    const float* root2 = (const float*)d_in[8];
    const float* bias2 = (const float*)d_in[9];

    const int N = in_sizes[0] / F_DIM;
    const int E = in_sizes[2];
    const int* srcp = ei;
    const int* dstp = ei + E;

    // ws layout (floats): mm[16] | ewn[E] | invc[N] | aggh[N*H] | xr[N*H] | projr[N*H]
    float* w     = (float*)d_ws;
    float* mm    = w;
    float* ewn   = w + 16;
    float* invc  = ewn + E;
    float* aggh  = invc + N;
    float* xr    = aggh + (size_t)N * H_DIM;
    float* projr = xr + (size_t)N * H_DIM;

    const int TB = 256;
    int blocksE = (E + TB - 1) / TB;

    // edge-weight min/max + normalize
    init_mm<<<1, 64, 0, stream>>>(mm);
    minmax_kernel<<<512, TB, 0, stream>>>(ew, E, mm);
    norm_kernel<<<blocksE, TB, 0, stream>>>(ew, ewn, mm, E);

    // degree counts -> inverse
    hipMemsetAsync(invc, 0, (size_t)N * sizeof(float), stream);
    count_kernel<<<blocksE, TB, 0, stream>>>(dstp, invc, E);
    invert_kernel<<<(N + TB - 1) / TB, TB, 0, stream>>>(invc, N);

    // ---------------- layer 1: F=128 -> H=128, relu ----------------
    hipMemsetAsync(aggh, 0, (size_t)N * H_DIM * sizeof(float), stream);
    dim3 g1((N + 63) / 64, H_DIM / 64);
    gemm_nn<<<g1, TB, 0, stream>>>(x, root1, xr, N, F_DIM, H_DIM);
    long st1 = (long)E * (H_DIM / 4);
    int scatB1 = (int)((st1 + TB - 1) / TB);
    for (int r = 0; r < R_NUM; ++r) {
        gemm_nn<<<g1, TB, 0, stream>>>(x, W1 + (size_t)r * F_DIM * H_DIM, projr,
                                       N, F_DIM, H_DIM);
        scatter_rel<H_DIM><<<scatB1, TB, 0, stream>>>(srcp, dstp, et, ewn, projr,
                                                      aggh, E, r);
    }
    long fin1 = (long)N * (H_DIM / 4);
    finalize_kernel<H_DIM, true><<<(int)((fin1 + TB - 1) / TB), TB, 0, stream>>>(
        aggh, xr, bias1, invc, aggh, N);  // h stored in-place in aggh

    // ---------------- layer 2: H=128 -> O=64, no relu ----------------
    float* xr2  = xr;                       // N*O
    float* agg2 = xr + (size_t)N * O_DIM;   // N*O (both fit in old xr slot)
    hipMemsetAsync(agg2, 0, (size_t)N * O_DIM * sizeof(float), stream);
    dim3 g2((N + 63) / 64, O_DIM / 64);
    gemm_nn<<<g2, TB, 0, stream>>>(aggh, root2, xr2, N, H_DIM, O_DIM);
    long st2 = (long)E * (O_DIM / 4);
    int scatB2 = (int)((st2 + TB - 1) / TB);
    for (int r = 0; r < R_NUM; ++r) {
        gemm_nn<<<g2, TB, 0, stream>>>(aggh, W2 + (size_t)r * H_DIM * O_DIM, projr,
                                       N, H_DIM, O_DIM);
        scatter_rel<O_DIM><<<scatB2, TB, 0, stream>>>(srcp, dstp, et, ewn, projr,
                                                      agg2, E, r);
    }
    long fin2 = (long)N * (O_DIM / 4);
    finalize_kernel<O_DIM, false><<<(int)((fin2 + TB - 1) / TB), TB, 0, stream>>>(
        agg2, xr2, bias2, invc, (float*)d_out, N);
}

// Round 2
// 1003.621 us; speedup vs baseline: 2.1617x; 2.1617x over previous
//
#include <hip/hip_runtime.h>

// Problem constants: N=50000, E=600000, F=128, H=128, O=64, R=8
#define F_DIM 128
#define H_DIM 128
#define O_DIM 64
#define R_NUM 8

// ---------------- min/max of edge weights (non-negative -> int-punned atomics) ----
__global__ void init_mm(float* mm) {
    if (threadIdx.x == 0) {
        ((int*)mm)[0] = 0x7f800000;  // +inf
        ((int*)mm)[1] = 0x00000000;  // 0.0f
    }
}

__global__ void minmax_kernel(const float* __restrict__ w, int E, float* mm) {
    __shared__ float smn[256], smx[256];
    int tid = threadIdx.x;
    float mn = 1e30f, mx = -1e30f;
    for (int i = blockIdx.x * blockDim.x + tid; i < E; i += gridDim.x * blockDim.x) {
        float v = w[i];
        mn = fminf(mn, v);
        mx = fmaxf(mx, v);
    }
    smn[tid] = mn; smx[tid] = mx;
    __syncthreads();
    for (int s = 128; s > 0; s >>= 1) {
        if (tid < s) {
            smn[tid] = fminf(smn[tid], smn[tid + s]);
            smx[tid] = fmaxf(smx[tid], smx[tid + s]);
        }
        __syncthreads();
    }
    if (tid == 0) {
        atomicMin((int*)mm + 0, __float_as_int(smn[0]));
        atomicMax((int*)mm + 1, __float_as_int(smx[0]));
    }
}

// ---------------- degree count + inverse --------------------------------------
__global__ void count_kernel(const int* __restrict__ dst, int* __restrict__ deg, int E) {
    int i = blockIdx.x * blockDim.x + threadIdx.x;
    if (i < E) atomicAdd(&deg[dst[i]], 1);
}

__global__ void invert_kernel(const int* __restrict__ deg, float* __restrict__ invc, int N) {
    int i = blockIdx.x * blockDim.x + threadIdx.x;
    if (i < N) invc[i] = 1.0f / (float)max(deg[i], 1);
}

// ---------------- exclusive scan of deg -> rp (3-kernel, 1024 elems/block) -----
__global__ void scan1_kernel(const int* __restrict__ deg, int* __restrict__ rp,
                             int* __restrict__ bsum, int N) {
    __shared__ int s[256];
    int base = blockIdx.x * 1024;
    int t = threadIdx.x;
    int v[4]; int loc = 0;
#pragma unroll
    for (int i = 0; i < 4; ++i) {
        int idx = base + t * 4 + i;
        v[i] = (idx < N) ? deg[idx] : 0;
        loc += v[i];
    }
    s[t] = loc;
    __syncthreads();
    // inclusive Hillis-Steele over 256 per-thread sums
    for (int off = 1; off < 256; off <<= 1) {
        int x = (t >= off) ? s[t - off] : 0;
        __syncthreads();
        s[t] += x;
        __syncthreads();
    }
    int run = s[t] - loc;  // exclusive prefix of this thread's chunk
#pragma unroll
    for (int i = 0; i < 4; ++i) {
        int idx = base + t * 4 + i;
        if (idx < N) rp[idx] = run;
        run += v[i];
    }
    if (t == 255) bsum[blockIdx.x] = s[255];
}

__global__ void scan2_kernel(int* bsum, int nb) {
    if (threadIdx.x == 0) {
        int running = 0;
        for (int b = 0; b < nb; ++b) { int x = bsum[b]; bsum[b] = running; running += x; }
    }
}

__global__ void scan3_kernel(int* __restrict__ rp, const int* __restrict__ bsum, int N) {
    int i = blockIdx.x * blockDim.x + threadIdx.x;
    if (i < N) rp[i] += bsum[i >> 10];
}

// ---------------- CSR fill (advances rp; afterwards rp[d] = end offset of d) ---
// packs src | et<<24 ; normalizes edge weight on the fly
__global__ void fill_kernel(const int* __restrict__ src, const int* __restrict__ dst,
                            const int* __restrict__ et, const float* __restrict__ ew,
                            const float* __restrict__ mm, int* __restrict__ rp,
                            int* __restrict__ packed, float* __restrict__ wsorted, int E) {
    int e = blockIdx.x * blockDim.x + threadIdx.x;
    if (e >= E) return;
    int d = dst[e];
    int pos = atomicAdd(&rp[d], 1);
    packed[pos] = src[e] | (et[e] << 24);
    float mn = mm[0], mx = mm[1];
    wsorted[pos] = (ew[e] - mn) / (mx - mn + 1e-8f);
}

// ---------------- fp32 tiled GEMM: C[MxNcol] = A[MxK] @ B[KxNcol] --------------
__global__ __launch_bounds__(256) void gemm_nn(const float* __restrict__ A,
                                               const float* __restrict__ B,
                                               float* __restrict__ C,
                                               int M, int K, int Ncol) {
    __shared__ float As[16][64];   // [k][m]
    __shared__ float Bs[16][64];   // [k][n]
    const int tid = threadIdx.x;
    const int bm = blockIdx.x * 64;
    const int bn = blockIdx.y * 64;
    const int tx = tid & 15;
    const int ty = tid >> 4;
    const int ar = tid >> 2;
    const int ac = (tid & 3) << 2;
    const int br = tid >> 4;
    const int bc = (tid & 15) << 2;
    int arow = bm + ar;
    if (arow >= M) arow = M - 1;

    float acc[4][4] = {};
    for (int k0 = 0; k0 < K; k0 += 16) {
        float4 av = *(const float4*)(A + (size_t)arow * K + k0 + ac);
        float4 bv = *(const float4*)(B + (size_t)(k0 + br) * Ncol + bn + bc);
        As[ac + 0][ar] = av.x; As[ac + 1][ar] = av.y;
        As[ac + 2][ar] = av.z; As[ac + 3][ar] = av.w;
        Bs[br][bc + 0] = bv.x; Bs[br][bc + 1] = bv.y;
        Bs[br][bc + 2] = bv.z; Bs[br][bc + 3] = bv.w;
        __syncthreads();
#pragma unroll
        for (int kk = 0; kk < 16; ++kk) {
            float a[4], b[4];
#pragma unroll
            for (int i = 0; i < 4; ++i) a[i] = As[kk][ty * 4 + i];
#pragma unroll
            for (int j = 0; j < 4; ++j) b[j] = Bs[kk][tx * 4 + j];
#pragma unroll
            for (int i = 0; i < 4; ++i)
#pragma unroll
                for (int j = 0; j < 4; ++j)
                    acc[i][j] += a[i] * b[j];
        }
        __syncthreads();
    }
#pragma unroll
    for (int i = 0; i < 4; ++i) {
        int row = bm + ty * 4 + i;
        if (row < M) {
            float4 o = make_float4(acc[i][0], acc[i][1], acc[i][2], acc[i][3]);
            *(float4*)(C + (size_t)row * Ncol + bn + tx * 4) = o;
        }
    }
}

// ---------------- CSR gather: agg[n] (+)= sum_{e in-edges of n, et==rel} w*proj[src] ----
template <int CH, bool FIRST>
__global__ void gather_rel(const int* __restrict__ rp, const int* __restrict__ packed,
                           const float* __restrict__ wsorted, const float* __restrict__ proj,
                           float* __restrict__ agg, int N, int rel) {
    constexpr int LPE = CH / 4;
    int gid = blockIdx.x * blockDim.x + threadIdx.x;
    int n = gid / LPE;
    if (n >= N) return;
    int j = (gid % LPE) * 4;
    int beg = (n == 0) ? 0 : rp[n - 1];
    int end = rp[n];
    float ax = 0.f, ay = 0.f, az = 0.f, aw = 0.f;
    bool hit = false;
    for (int k = beg; k < end; ++k) {
        int p = packed[k];
        if ((p >> 24) != rel) continue;
        hit = true;
        float w = wsorted[k];
        const float4 v = *(const float4*)(proj + (size_t)(p & 0xFFFFFF) * CH + j);
        ax += w * v.x; ay += w * v.y; az += w * v.z; aw += w * v.w;
    }
    float* o = agg + (size_t)n * CH + j;
    if (FIRST) {
        *(float4*)o = make_float4(ax, ay, az, aw);
    } else if (hit) {
        float4 cur = *(const float4*)o;
        cur.x += ax; cur.y += ay; cur.z += az; cur.w += aw;
        *(float4*)o = cur;
    }
}

// ---------------- finalize: out = agg*inv_cnt + xr + bias (opt relu) -----------
template <int CH, bool RELU>
__global__ void finalize_kernel(const float* __restrict__ agg, const float* __restrict__ xr,
                                const float* __restrict__ bias, const float* __restrict__ invc,
                                float* __restrict__ out, int N) {
    constexpr int LPE = CH / 4;
    int gid = blockIdx.x * blockDim.x + threadIdx.x;
    int n = gid / LPE;
    if (n >= N) return;
    int j = (gid % LPE) * 4;
    float inv = invc[n];
    float4 a = *(const float4*)(agg + (size_t)n * CH + j);
    float4 x = *(const float4*)(xr + (size_t)n * CH + j);
    float4 b = *(const float4*)(bias + j);
    float4 o;
    o.x = a.x * inv + x.x + b.x;
    o.y = a.y * inv + x.y + b.y;
    o.z = a.z * inv + x.z + b.z;
    o.w = a.w * inv + x.w + b.w;
    if (RELU) {
        o.x = fmaxf(o.x, 0.0f); o.y = fmaxf(o.y, 0.0f);
        o.z = fmaxf(o.z, 0.0f); o.w = fmaxf(o.w, 0.0f);
    }
    *(float4*)(out + (size_t)n * CH + j) = o;
}

extern "C" void kernel_launch(void* const* d_in, const int* in_sizes, int n_in,
                              void* d_out, int out_size, void* d_ws, size_t ws_size,
                              hipStream_t stream) {
    const float* x     = (const float*)d_in[0];
    const int*   ei    = (const int*)d_in[1];
    const float* ew    = (const float*)d_in[2];
    const int*   et    = (const int*)d_in[3];
    const float* W1    = (const float*)d_in[4];
    const float* root1 = (const float*)d_in[5];
    const float* bias1 = (const float*)d_in[6];
    const float* W2    = (const float*)d_in[7];
    const float* root2 = (const float*)d_in[8];
    const float* bias2 = (const float*)d_in[9];

    const int N = in_sizes[0] / F_DIM;
    const int E = in_sizes[2];
    const int* srcp = ei;
    const int* dstp = ei + E;

    // ws layout (4B units):
    // mm[16] | invc[N] | deg[N] | rp[N] | bsum[64] | packed[E] | wsorted[E]
    // | aggh[N*128] | xr[N*128] | projr[N*128]
    float* w      = (float*)d_ws;
    float* mm     = w;
    float* invc   = w + 16;
    int*   deg    = (int*)(invc + N);
    int*   rp     = deg + N;
    int*   bsum   = rp + N;
    int*   packed = bsum + 64;
    float* wsortd = (float*)(packed + E);
    float* aggh   = wsortd + E;
    float* xr     = aggh + (size_t)N * H_DIM;
    float* projr  = xr + (size_t)N * H_DIM;

    const int TB = 256;
    int blocksE = (E + TB - 1) / TB;
    int blocksN = (N + TB - 1) / TB;
    int nb = (N + 1023) / 1024;

    // edge-weight min/max
    init_mm<<<1, 64, 0, stream>>>(mm);
    minmax_kernel<<<512, TB, 0, stream>>>(ew, E, mm);

    // degree count -> invc ; exclusive scan -> rp ; CSR fill (advances rp)
    hipMemsetAsync(deg, 0, (size_t)N * sizeof(int), stream);
    count_kernel<<<blocksE, TB, 0, stream>>>(dstp, deg, E);
    invert_kernel<<<blocksN, TB, 0, stream>>>(deg, invc, N);
    scan1_kernel<<<nb, TB, 0, stream>>>(deg, rp, bsum, N);
    scan2_kernel<<<1, 64, 0, stream>>>(bsum, nb);
    scan3_kernel<<<blocksN, TB, 0, stream>>>(rp, bsum, N);
    fill_kernel<<<blocksE, TB, 0, stream>>>(srcp, dstp, et, ew, mm, rp, packed, wsortd, E);

    // ---------------- layer 1: F=128 -> H=128, relu ----------------
    dim3 g1((N + 63) / 64, H_DIM / 64);
    gemm_nn<<<g1, TB, 0, stream>>>(x, root1, xr, N, F_DIM, H_DIM);
    long th1 = (long)N * (H_DIM / 4);
    int gatB1 = (int)((th1 + TB - 1) / TB);
    for (int r = 0; r < R_NUM; ++r) {
        gemm_nn<<<g1, TB, 0, stream>>>(x, W1 + (size_t)r * F_DIM * H_DIM, projr,
                                       N, F_DIM, H_DIM);
        if (r == 0)
            gather_rel<H_DIM, true><<<gatB1, TB, 0, stream>>>(rp, packed, wsortd, projr,
                                                              aggh, N, r);
        else
            gather_rel<H_DIM, false><<<gatB1, TB, 0, stream>>>(rp, packed, wsortd, projr,
                                                               aggh, N, r);
    }
    finalize_kernel<H_DIM, true><<<gatB1, TB, 0, stream>>>(aggh, xr, bias1, invc, aggh, N);

    // ---------------- layer 2: H=128 -> O=64, no relu ----------------
    float* xr2  = xr;                       // N*O
    float* agg2 = xr + (size_t)N * O_DIM;   // N*O
    dim3 g2((N + 63) / 64, O_DIM / 64);
    gemm_nn<<<g2, TB, 0, stream>>>(aggh, root2, xr2, N, H_DIM, O_DIM);
    long th2 = (long)N * (O_DIM / 4);
    int gatB2 = (int)((th2 + TB - 1) / TB);
    for (int r = 0; r < R_NUM; ++r) {
        gemm_nn<<<g2, TB, 0, stream>>>(aggh, W2 + (size_t)r * H_DIM * O_DIM, projr,
                                       N, H_DIM, O_DIM);
        if (r == 0)
            gather_rel<O_DIM, true><<<gatB2, TB, 0, stream>>>(rp, packed, wsortd, projr,
                                                              agg2, N, r);
        else
            gather_rel<O_DIM, false><<<gatB2, TB, 0, stream>>>(rp, packed, wsortd, projr,
                                                               agg2, N, r);
    }
    finalize_kernel<O_DIM, false><<<gatB2, TB, 0, stream>>>(agg2, xr2, bias2, invc,
                                                            (float*)d_out, N);
}

// Round 3
// 747.701 us; speedup vs baseline: 2.9016x; 1.3423x over previous
//
#include <hip/hip_runtime.h>

// Problem constants: N=50000, E=600000, F=128, H=128, O=64, R=8
#define F_DIM 128
#define H_DIM 128
#define O_DIM 64
#define R_NUM 8

typedef __attribute__((ext_vector_type(8))) short bf16x8;
typedef __attribute__((ext_vector_type(4))) float f32x4;

__device__ __forceinline__ unsigned short f2b(float f) {
    unsigned u = __float_as_uint(f);
    u += 0x7FFFu + ((u >> 16) & 1u);   // RNE
    return (unsigned short)(u >> 16);
}
__device__ __forceinline__ float b2f(unsigned short b) {
    return __uint_as_float(((unsigned)b) << 16);
}

// ---------------- min/max of edge weights ----------------
__global__ void init_mm(float* mm) {
    if (threadIdx.x == 0) {
        ((int*)mm)[0] = 0x7f800000;  // +inf
        ((int*)mm)[1] = 0x00000000;  // 0.0f (weights are >= 0)
    }
}

__global__ void minmax_kernel(const float* __restrict__ w, int E, float* mm) {
    __shared__ float smn[256], smx[256];
    int tid = threadIdx.x;
    float mn = 1e30f, mx = -1e30f;
    for (int i = blockIdx.x * blockDim.x + tid; i < E; i += gridDim.x * blockDim.x) {
        float v = w[i];
        mn = fminf(mn, v);
        mx = fmaxf(mx, v);
    }
    smn[tid] = mn; smx[tid] = mx;
    __syncthreads();
    for (int s = 128; s > 0; s >>= 1) {
        if (tid < s) {
            smn[tid] = fminf(smn[tid], smn[tid + s]);
            smx[tid] = fmaxf(smx[tid], smx[tid + s]);
        }
        __syncthreads();
    }
    if (tid == 0) {
        atomicMin((int*)mm + 0, __float_as_int(smn[0]));
        atomicMax((int*)mm + 1, __float_as_int(smx[0]));
    }
}

// ---------------- conversions ----------------
// fp32 -> bf16, n4 = count/4
__global__ void convert_bf16(const float* __restrict__ in, unsigned short* __restrict__ out,
                             long n4) {
    long i = (long)blockIdx.x * blockDim.x + threadIdx.x;
    if (i >= n4) return;
    float4 v = ((const float4*)in)[i];
    ushort4 o;
    o.x = f2b(v.x); o.y = f2b(v.y); o.z = f2b(v.z); o.w = f2b(v.w);
    ((ushort4*)out)[i] = o;
}

// W [8][K][Ncol] + root [K][Ncol]  ->  Wt [9][Ncol][K] bf16 (transposed)
__global__ void conv_wt(const float* __restrict__ W, const float* __restrict__ root,
                        unsigned short* __restrict__ Wt, int K, int Ncol) {
    int idx = blockIdx.x * blockDim.x + threadIdx.x;
    int total = 9 * K * Ncol;
    if (idx >= total) return;
    int r = idx / (K * Ncol);
    int rem = idx % (K * Ncol);
    int n = rem / K;
    int k = rem % K;
    float v = (r < 8) ? W[((size_t)r * K + k) * Ncol + n] : root[(size_t)k * Ncol + n];
    Wt[idx] = f2b(v);
}

// ---------------- CSR by (dst, rel): count / scan / fill ----------------
__global__ void count2_kernel(const int* __restrict__ dst, const int* __restrict__ et,
                              int* __restrict__ deg2, int E) {
    int i = blockIdx.x * blockDim.x + threadIdx.x;
    if (i < E) atomicAdd(&deg2[dst[i] * R_NUM + et[i]], 1);
}

__global__ void invert2_kernel(const int* __restrict__ deg2, float* __restrict__ invc, int N) {
    int n = blockIdx.x * blockDim.x + threadIdx.x;
    if (n >= N) return;
    const int4* p = (const int4*)(deg2 + (size_t)n * R_NUM);
    int4 a = p[0], b = p[1];
    int s = a.x + a.y + a.z + a.w + b.x + b.y + b.z + b.w;
    invc[n] = 1.0f / (float)max(s, 1);
}

// exclusive scan of deg2[M] -> rp2[M] (1024 elems per block)
__global__ void scan1_kernel(const int* __restrict__ deg, int* __restrict__ rp,
                             int* __restrict__ bsum, int M) {
    __shared__ int s[256];
    int base = blockIdx.x * 1024;
    int t = threadIdx.x;
    int v[4]; int loc = 0;
#pragma unroll
    for (int i = 0; i < 4; ++i) {
        int idx = base + t * 4 + i;
        v[i] = (idx < M) ? deg[idx] : 0;
        loc += v[i];
    }
    s[t] = loc;
    __syncthreads();
    for (int off = 1; off < 256; off <<= 1) {
        int x = (t >= off) ? s[t - off] : 0;
        __syncthreads();
        s[t] += x;
        __syncthreads();
    }
    int run = s[t] - loc;
#pragma unroll
    for (int i = 0; i < 4; ++i) {
        int idx = base + t * 4 + i;
        if (idx < M) rp[idx] = run;
        run += v[i];
    }
    if (t == 255) bsum[blockIdx.x] = s[255];
}

__global__ void scan2_kernel(int* bsum, int nb) {
    if (threadIdx.x == 0) {
        int running = 0;
        for (int b = 0; b < nb; ++b) { int x = bsum[b]; bsum[b] = running; running += x; }
    }
}

__global__ void scan3_kernel(int* __restrict__ rp, const int* __restrict__ bsum, int M) {
    int i = blockIdx.x * blockDim.x + threadIdx.x;
    if (i < M) rp[i] += bsum[i >> 10];
}

// fill: pos = rp2[dst*8+rel]++ ; erec[pos] = {src, w_norm_bits}
__global__ void fill2_kernel(const int* __restrict__ src, const int* __restrict__ dst,
                             const int* __restrict__ et, const float* __restrict__ ew,
                             const float* __restrict__ mm, int* __restrict__ rp2,
                             int2* __restrict__ erec, int E) {
    int e = blockIdx.x * blockDim.x + threadIdx.x;
    if (e >= E) return;
    int pos = atomicAdd(&rp2[dst[e] * R_NUM + et[e]], 1);
    float mn = mm[0], mx = mm[1];
    erec[pos] = make_int2(src[e], __float_as_int((ew[e] - mn) / (mx - mn + 1e-8f)));
}

// ---------------- MFMA GEMM: C[M x NCOL] = A[M x 128] @ Bt[NCOL x 128]^T ------
// A, Bt bf16. MODE 0: store C as bf16 to outb. MODE 1/2: finalize
// outf = (agg*invc + C + bias) [relu if MODE 1].
// block = 256 threads (4 waves), tile 64 rows x NCOL cols, K=128 in one sweep.
template <int NCOL, int MODE>
__global__ __launch_bounds__(256) void gemm_mfma(
    const unsigned short* __restrict__ A,
    const unsigned short* __restrict__ Bt,
    unsigned short* __restrict__ outb,
    const float* __restrict__ agg,
    const float* __restrict__ invc,
    const float* __restrict__ bias,
    float* __restrict__ outf,
    int M)
{
    constexpr int NT = NCOL / 16;
    const int wave = threadIdx.x >> 6;
    const int lane = threadIdx.x & 63;
    const int quad = lane >> 4;
    const int l15 = lane & 15;
    const int R0 = blockIdx.x * 64 + wave * 16;
    int row = R0 + l15;
    if (row >= M) row = M - 1;  // clamp loads; stores guarded

    // preload A fragments for all 4 k-steps (k = kk*32 + quad*8 + j)
    const bf16x8* ap = (const bf16x8*)(A + (size_t)row * 128 + quad * 8);
    bf16x8 a[4];
#pragma unroll
    for (int kk = 0; kk < 4; ++kk) a[kk] = ap[kk * 4];

    f32x4 acc[NT];
#pragma unroll
    for (int nt = 0; nt < NT; ++nt) acc[nt] = (f32x4){0.f, 0.f, 0.f, 0.f};

#pragma unroll
    for (int kk = 0; kk < 4; ++kk) {
#pragma unroll
        for (int nt = 0; nt < NT; ++nt) {
            bf16x8 b = *(const bf16x8*)(Bt + ((size_t)(nt * 16 + l15)) * 128 + kk * 32 + quad * 8);
            acc[nt] = __builtin_amdgcn_mfma_f32_16x16x32_bf16(a[kk], b, acc[nt], 0, 0, 0);
        }
    }

#pragma unroll
    for (int nt = 0; nt < NT; ++nt) {
#pragma unroll
        for (int i = 0; i < 4; ++i) {
            int r = R0 + quad * 4 + i;   // D: row = quad*4 + reg, col = lane&15
            int c = nt * 16 + l15;
            if (r < M) {
                if (MODE == 0) {
                    outb[(size_t)r * NCOL + c] = f2b(acc[nt][i]);
                } else {
                    float v = agg[(size_t)r * NCOL + c] * invc[r] + acc[nt][i] + bias[c];
                    if (MODE == 1) v = fmaxf(v, 0.f);
                    outf[(size_t)r * NCOL + c] = v;
                }
            }
        }
    }
}

// ---------------- CSR gather over segment (n, rel): agg (+)= sum w*proj[src] --
template <int CH, bool FIRST>
__global__ void gather_rel(const int* __restrict__ rp2, const int2* __restrict__ erec,
                           const unsigned short* __restrict__ projb,
                           float* __restrict__ agg, int N, int rel) {
    constexpr int LPE = CH / 4;
    int gid = blockIdx.x * blockDim.x + threadIdx.x;
    int n = gid / LPE;
    if (n >= N) return;
    int j = (gid % LPE) * 4;
    int i = n * R_NUM + rel;
    int beg = (i == 0) ? 0 : rp2[i - 1];
    int end = rp2[i];
    float ax = 0.f, ay = 0.f, az = 0.f, aw = 0.f;
    for (int k = beg; k < end; ++k) {
        int2 e = erec[k];
        float w = __int_as_float(e.y);
        ushort4 v = *(const ushort4*)(projb + (size_t)e.x * CH + j);
        ax += w * b2f(v.x); ay += w * b2f(v.y);
        az += w * b2f(v.z); aw += w * b2f(v.w);
    }
    float* o = agg + (size_t)n * CH + j;
    if (FIRST) {
        *(float4*)o = make_float4(ax, ay, az, aw);
    } else if (end > beg) {
        float4 cur = *(const float4*)o;
        cur.x += ax; cur.y += ay; cur.z += az; cur.w += aw;
        *(float4*)o = cur;
    }
}

extern "C" void kernel_launch(void* const* d_in, const int* in_sizes, int n_in,
                              void* d_out, int out_size, void* d_ws, size_t ws_size,
                              hipStream_t stream) {
    const float* x     = (const float*)d_in[0];
    const int*   ei    = (const int*)d_in[1];
    const float* ew    = (const float*)d_in[2];
    const int*   et    = (const int*)d_in[3];
    const float* W1    = (const float*)d_in[4];
    const float* root1 = (const float*)d_in[5];
    const float* bias1 = (const float*)d_in[6];
    const float* W2    = (const float*)d_in[7];
    const float* root2 = (const float*)d_in[8];
    const float* bias2 = (const float*)d_in[9];

    const int N = in_sizes[0] / F_DIM;
    const int E = in_sizes[2];
    const int M2 = N * R_NUM;
    const int* srcp = ei;
    const int* dstp = ei + E;

    // ws layout (int units):
    // mm[16] | invc[N] | deg2[8N] | rp2[8N] | bsum[512] | erec[2E] |
    // xb[N*128 bf16 = N*64] | wt1[9*128*128 bf16] | wt2[9*64*128 bf16] |
    // projb[N*128 bf16] | aggh[N*128 f32] | agg2[N*64 f32]   (~73 MB)
    int* base = (int*)d_ws;
    float* mm    = (float*)base;
    float* invc  = (float*)(base + 16);
    int*   deg2  = base + 16 + N;
    int*   rp2   = deg2 + M2;
    int*   bsum  = rp2 + M2;
    int2*  erec  = (int2*)(bsum + 512);
    unsigned short* xb    = (unsigned short*)(bsum + 512 + 2 * E);
    unsigned short* wt1   = xb + (size_t)N * 128;
    unsigned short* wt2   = wt1 + 9 * 128 * 128;
    unsigned short* projb = wt2 + 9 * 64 * 128;
    float* aggh = (float*)(projb + (size_t)N * 128);
    float* agg2 = aggh + (size_t)N * 128;

    const int TB = 256;
    int blocksE = (E + TB - 1) / TB;
    int blocksN = (N + TB - 1) / TB;
    int nb = (M2 + 1023) / 1024;

    // setup: minmax, conversions, CSR
    init_mm<<<1, 64, 0, stream>>>(mm);
    minmax_kernel<<<512, TB, 0, stream>>>(ew, E, mm);
    long x4 = (long)N * 128 / 4;
    convert_bf16<<<(int)((x4 + TB - 1) / TB), TB, 0, stream>>>(x, xb, x4);
    int wt1n = 9 * 128 * 128, wt2n = 9 * 64 * 128;
    conv_wt<<<(wt1n + TB - 1) / TB, TB, 0, stream>>>(W1, root1, wt1, F_DIM, H_DIM);
    conv_wt<<<(wt2n + TB - 1) / TB, TB, 0, stream>>>(W2, root2, wt2, H_DIM, O_DIM);
    hipMemsetAsync(deg2, 0, (size_t)M2 * sizeof(int), stream);
    count2_kernel<<<blocksE, TB, 0, stream>>>(dstp, et, deg2, E);
    scan1_kernel<<<nb, TB, 0, stream>>>(deg2, rp2, bsum, M2);
    scan2_kernel<<<1, 64, 0, stream>>>(bsum, nb);
    scan3_kernel<<<(M2 + TB - 1) / TB, TB, 0, stream>>>(rp2, bsum, M2);
    invert2_kernel<<<blocksN, TB, 0, stream>>>(deg2, invc, N);
    fill2_kernel<<<blocksE, TB, 0, stream>>>(srcp, dstp, et, ew, mm, rp2, erec, E);

    int gemmB = (N + 63) / 64;
    // ---------------- layer 1: F=128 -> H=128, relu ----------------
    long g1t = (long)N * (H_DIM / 4);
    int gatB1 = (int)((g1t + TB - 1) / TB);
    for (int r = 0; r < R_NUM; ++r) {
        gemm_mfma<H_DIM, 0><<<gemmB, TB, 0, stream>>>(
            xb, wt1 + (size_t)r * 128 * 128, projb, nullptr, nullptr, nullptr, nullptr, N);
        if (r == 0)
            gather_rel<H_DIM, true><<<gatB1, TB, 0, stream>>>(rp2, erec, projb, aggh, N, r);
        else
            gather_rel<H_DIM, false><<<gatB1, TB, 0, stream>>>(rp2, erec, projb, aggh, N, r);
    }
    // root transform + finalize (relu), h written in-place into aggh
    gemm_mfma<H_DIM, 1><<<gemmB, TB, 0, stream>>>(
        xb, wt1 + (size_t)8 * 128 * 128, nullptr, aggh, invc, bias1, aggh, N);
    // h -> bf16 (reuse xb)
    convert_bf16<<<(int)((x4 + TB - 1) / TB), TB, 0, stream>>>(aggh, xb, x4);

    // ---------------- layer 2: H=128 -> O=64, no relu ----------------
    long g2t = (long)N * (O_DIM / 4);
    int gatB2 = (int)((g2t + TB - 1) / TB);
    for (int r = 0; r < R_NUM; ++r) {
        gemm_mfma<O_DIM, 0><<<gemmB, TB, 0, stream>>>(
            xb, wt2 + (size_t)r * 64 * 128, projb, nullptr, nullptr, nullptr, nullptr, N);
        if (r == 0)
            gather_rel<O_DIM, true><<<gatB2, TB, 0, stream>>>(rp2, erec, projb, agg2, N, r);
        else
            gather_rel<O_DIM, false><<<gatB2, TB, 0, stream>>>(rp2, erec, projb, agg2, N, r);
    }
    gemm_mfma<O_DIM, 2><<<gemmB, TB, 0, stream>>>(
        xb, wt2 + (size_t)8 * 64 * 128, nullptr, agg2, invc, bias2, (float*)d_out, N);
}

// Round 4
// 472.983 us; speedup vs baseline: 4.5869x; 1.5808x over previous
//
#include <hip/hip_runtime.h>

// Problem constants: N=50000, E=600000, F=128, H=128, O=64, R=8
#define F_DIM 128
#define H_DIM 128
#define O_DIM 64
#define R_NUM 8

typedef __attribute__((ext_vector_type(8))) short bf16x8;
typedef __attribute__((ext_vector_type(4))) float f32x4;
typedef __attribute__((ext_vector_type(8))) unsigned short u16x8;
typedef __attribute__((ext_vector_type(4))) unsigned short u16x4;

__device__ __forceinline__ unsigned short f2b(float f) {
    unsigned u = __float_as_uint(f);
    u += 0x7FFFu + ((u >> 16) & 1u);   // RNE
    return (unsigned short)(u >> 16);
}
__device__ __forceinline__ float b2f(unsigned short b) {
    return __uint_as_float(((unsigned)b) << 16);
}

// ---------------- init min/max cell ----------------
__global__ void init_mm(float* mm) {
    if (threadIdx.x == 0) {
        ((int*)mm)[0] = 0x7f800000;  // +inf
        ((int*)mm)[1] = 0x00000000;  // 0.0f (weights >= 0)
    }
}

// ---------------- fused: degree count (atomic) + edge-weight min/max ----------
__global__ void count_minmax(const float* __restrict__ ew, const int* __restrict__ dst,
                             int* __restrict__ deg, float* __restrict__ mm, int E) {
    __shared__ float smn[256], smx[256];
    int tid = threadIdx.x;
    float mn = 1e30f, mx = -1e30f;
    for (int i = blockIdx.x * blockDim.x + tid; i < E; i += gridDim.x * blockDim.x) {
        atomicAdd(&deg[dst[i]], 1);
        float v = ew[i];
        mn = fminf(mn, v);
        mx = fmaxf(mx, v);
    }
    smn[tid] = mn; smx[tid] = mx;
    __syncthreads();
    for (int s = 128; s > 0; s >>= 1) {
        if (tid < s) {
            smn[tid] = fminf(smn[tid], smn[tid + s]);
            smx[tid] = fmaxf(smx[tid], smx[tid + s]);
        }
        __syncthreads();
    }
    if (tid == 0) {
        atomicMin((int*)mm + 0, __float_as_int(smn[0]));
        atomicMax((int*)mm + 1, __float_as_int(smx[0]));
    }
}

// ---------------- conversions ----------------
__global__ void convert_bf16(const float* __restrict__ in, unsigned short* __restrict__ out,
                             long n4) {
    long i = (long)blockIdx.x * blockDim.x + threadIdx.x;
    if (i >= n4) return;
    float4 v = ((const float4*)in)[i];
    ushort4 o;
    o.x = f2b(v.x); o.y = f2b(v.y); o.z = f2b(v.z); o.w = f2b(v.w);
    ((ushort4*)out)[i] = o;
}

// W [8][K][Ncol] + root [K][Ncol] -> Wt [9][Ncol][K] bf16 (transposed)
__global__ void conv_wt(const float* __restrict__ W, const float* __restrict__ root,
                        unsigned short* __restrict__ Wt, int K, int Ncol) {
    int idx = blockIdx.x * blockDim.x + threadIdx.x;
    int total = 9 * K * Ncol;
    if (idx >= total) return;
    int r = idx / (K * Ncol);
    int rem = idx % (K * Ncol);
    int n = rem / K;
    int k = rem % K;
    float v = (r < 8) ? W[((size_t)r * K + k) * Ncol + n] : root[(size_t)k * Ncol + n];
    Wt[idx] = f2b(v);
}

// ---------------- scan (node-level CSR) ----------------
// scan1: per-1024 chunk exclusive scan of deg -> rp, block sums -> bsum; also invc
__global__ void scan1_kernel(const int* __restrict__ deg, int* __restrict__ rp,
                             int* __restrict__ bsum, float* __restrict__ invc, int M) {
    __shared__ int s[256];
    int base = blockIdx.x * 1024;
    int t = threadIdx.x;
    int v[4]; int loc = 0;
#pragma unroll
    for (int i = 0; i < 4; ++i) {
        int idx = base + t * 4 + i;
        v[i] = (idx < M) ? deg[idx] : 0;
        if (idx < M) invc[idx] = 1.0f / (float)max(v[i], 1);
        loc += v[i];
    }
    s[t] = loc;
    __syncthreads();
    for (int off = 1; off < 256; off <<= 1) {
        int x = (t >= off) ? s[t - off] : 0;
        __syncthreads();
        s[t] += x;
        __syncthreads();
    }
    int run = s[t] - loc;
#pragma unroll
    for (int i = 0; i < 4; ++i) {
        int idx = base + t * 4 + i;
        if (idx < M) rp[idx] = run;
        run += v[i];
    }
    if (t == 255) bsum[blockIdx.x] = s[255];
}

// scan2: parallel exclusive scan of bsum (nb <= 256)
__global__ void scan2_kernel(int* bsum, int nb) {
    __shared__ int s[256];
    int t = threadIdx.x;
    int v = (t < nb) ? bsum[t] : 0;
    s[t] = v;
    __syncthreads();
    for (int off = 1; off < 256; off <<= 1) {
        int x = (t >= off) ? s[t - off] : 0;
        __syncthreads();
        s[t] += x;
        __syncthreads();
    }
    if (t < nb) bsum[t] = s[t] - v;
}

__global__ void scan3_kernel(int* __restrict__ rp, const int* __restrict__ bsum, int M) {
    int i = blockIdx.x * blockDim.x + threadIdx.x;
    if (i < M) rp[i] += bsum[i >> 10];
}

// ---------------- CSR fill: pos = rp[dst]++ ; erec = {src|rel<<24, w_norm} ----
__global__ void fill_kernel(const int* __restrict__ src, const int* __restrict__ dst,
                            const int* __restrict__ et, const float* __restrict__ ew,
                            const float* __restrict__ mm, int* __restrict__ rp,
                            int2* __restrict__ erec, int E) {
    int e = blockIdx.x * blockDim.x + threadIdx.x;
    if (e >= E) return;
    int pos = atomicAdd(&rp[dst[e]], 1);
    float mn = mm[0], mx = mm[1];
    erec[pos] = make_int2(src[e] | (et[e] << 24),
                          __float_as_int((ew[e] - mn) / (mx - mn + 1e-8f)));
}

// ---------------- MFMA proj gemm: proj[n][r][c] = sum_k x[n][k] W_r[k][c] -----
// Role-swapped MFMA: D = Wt_tile (M=outcols) x  x_tile (N=nodes).
// D: row(quad*4+i)=outcol-in-tile, col(lane&15)=node -> lane stores 4
// consecutive channels of one node as packed 8B ushort4.
template <int NCOL>
__global__ __launch_bounds__(256) void gemm_proj(const unsigned short* __restrict__ A,
                                                 const unsigned short* __restrict__ Wt,
                                                 unsigned short* __restrict__ proj, int M) {
    constexpr int NT = NCOL / 16;
    const int wave = threadIdx.x >> 6, lane = threadIdx.x & 63;
    const int quad = lane >> 4, l15 = lane & 15;
    const int n0 = blockIdx.x * 64 + wave * 16;
    int nld = n0 + l15;
    if (nld >= M) nld = M - 1;
    const unsigned short* ap = A + (size_t)nld * 128 + quad * 8;
    bf16x8 b[4];
#pragma unroll
    for (int kk = 0; kk < 4; ++kk) b[kk] = *(const bf16x8*)(ap + kk * 32);
    const int nst = n0 + l15;

    for (int r = 0; r < R_NUM; ++r) {
        f32x4 acc[NT];
#pragma unroll
        for (int nt = 0; nt < NT; ++nt) acc[nt] = (f32x4){0.f, 0.f, 0.f, 0.f};
#pragma unroll
        for (int kk = 0; kk < 4; ++kk) {
#pragma unroll
            for (int nt = 0; nt < NT; ++nt) {
                bf16x8 a = *(const bf16x8*)(Wt + ((size_t)r * NCOL + nt * 16 + l15) * 128
                                            + kk * 32 + quad * 8);
                acc[nt] = __builtin_amdgcn_mfma_f32_16x16x32_bf16(a, b[kk], acc[nt], 0, 0, 0);
            }
        }
        if (nst < M) {
#pragma unroll
            for (int nt = 0; nt < NT; ++nt) {
                int c0 = nt * 16 + quad * 4;
                u16x4 o;
#pragma unroll
                for (int i = 0; i < 4; ++i) o[i] = f2b(acc[nt][i]);
                *(u16x4*)(proj + ((size_t)nst * R_NUM + r) * NCOL + c0) = o;
            }
        }
    }
}

// ---------------- MFMA finalize gemm: out = agg*invc + A@Wroot + bias --------
template <int NCOL, bool RELU, bool OUTB>
__global__ __launch_bounds__(256) void gemm_fin(const unsigned short* __restrict__ A,
                                                const unsigned short* __restrict__ Wroot,
                                                const float* __restrict__ agg,
                                                const float* __restrict__ invc,
                                                const float* __restrict__ bias,
                                                unsigned short* __restrict__ outb,
                                                float* __restrict__ outf, int M) {
    constexpr int NT = NCOL / 16;
    const int wave = threadIdx.x >> 6, lane = threadIdx.x & 63;
    const int quad = lane >> 4, l15 = lane & 15;
    const int n0 = blockIdx.x * 64 + wave * 16;
    int nld = n0 + l15;
    if (nld >= M) nld = M - 1;
    const unsigned short* ap = A + (size_t)nld * 128 + quad * 8;
    bf16x8 b[4];
#pragma unroll
    for (int kk = 0; kk < 4; ++kk) b[kk] = *(const bf16x8*)(ap + kk * 32);

    f32x4 acc[NT];
#pragma unroll
    for (int nt = 0; nt < NT; ++nt) acc[nt] = (f32x4){0.f, 0.f, 0.f, 0.f};
#pragma unroll
    for (int kk = 0; kk < 4; ++kk) {
#pragma unroll
        for (int nt = 0; nt < NT; ++nt) {
            bf16x8 a = *(const bf16x8*)(Wroot + ((size_t)(nt * 16 + l15)) * 128
                                        + kk * 32 + quad * 8);
            acc[nt] = __builtin_amdgcn_mfma_f32_16x16x32_bf16(a, b[kk], acc[nt], 0, 0, 0);
        }
    }
    const int node = n0 + l15;
    if (node < M) {
        float inv = invc[node];
#pragma unroll
        for (int nt = 0; nt < NT; ++nt) {
            int c0 = nt * 16 + quad * 4;
            float4 g = *(const float4*)(agg + (size_t)node * NCOL + c0);
            float4 bs = *(const float4*)(bias + c0);
            float v0 = g.x * inv + acc[nt][0] + bs.x;
            float v1 = g.y * inv + acc[nt][1] + bs.y;
            float v2 = g.z * inv + acc[nt][2] + bs.z;
            float v3 = g.w * inv + acc[nt][3] + bs.w;
            if (RELU) {
                v0 = fmaxf(v0, 0.f); v1 = fmaxf(v1, 0.f);
                v2 = fmaxf(v2, 0.f); v3 = fmaxf(v3, 0.f);
            }
            if (OUTB) {
                u16x4 o = {f2b(v0), f2b(v1), f2b(v2), f2b(v3)};
                *(u16x4*)(outb + (size_t)node * NCOL + c0) = o;
            } else {
                *(float4*)(outf + (size_t)node * NCOL + c0) = make_float4(v0, v1, v2, v3);
            }
        }
    }
}

// ---------------- single-pass gather: agg[n] = sum_{e in(n)} w * proj[src][rel] ----
template <int CH>
__global__ void gather_all(const int* __restrict__ rp, const int2* __restrict__ erec,
                           const unsigned short* __restrict__ proj,
                           float* __restrict__ agg, int N) {
    constexpr int LPN = CH / 8;  // lanes per node (16 for CH=128, 8 for CH=64)
    int gid = blockIdx.x * blockDim.x + threadIdx.x;
    int n = gid / LPN;
    if (n >= N) return;
    int j = (gid % LPN) * 8;
    int beg = (n == 0) ? 0 : rp[n - 1];
    int end = rp[n];
    float acc[8] = {0.f, 0.f, 0.f, 0.f, 0.f, 0.f, 0.f, 0.f};
    for (int k = beg; k < end; ++k) {
        int2 e = erec[k];
        float w = __int_as_float(e.y);
        const u16x8 v = *(const u16x8*)(proj +
            ((size_t)(e.x & 0xFFFFFF) * R_NUM + (e.x >> 24)) * CH + j);
#pragma unroll
        for (int i = 0; i < 8; ++i) acc[i] += w * b2f(v[i]);
    }
    float* o = agg + (size_t)n * CH + j;
    *(float4*)o = make_float4(acc[0], acc[1], acc[2], acc[3]);
    *(float4*)(o + 4) = make_float4(acc[4], acc[5], acc[6], acc[7]);
}

extern "C" void kernel_launch(void* const* d_in, const int* in_sizes, int n_in,
                              void* d_out, int out_size, void* d_ws, size_t ws_size,
                              hipStream_t stream) {
    const float* x     = (const float*)d_in[0];
    const int*   ei    = (const int*)d_in[1];
    const float* ew    = (const float*)d_in[2];
    const int*   et    = (const int*)d_in[3];
    const float* W1    = (const float*)d_in[4];
    const float* root1 = (const float*)d_in[5];
    const float* bias1 = (const float*)d_in[6];
    const float* W2    = (const float*)d_in[7];
    const float* root2 = (const float*)d_in[8];
    const float* bias2 = (const float*)d_in[9];

    const int N = in_sizes[0] / F_DIM;
    const int E = in_sizes[2];
    const int* srcp = ei;
    const int* dstp = ei + E;

    // ws layout (int units unless noted):
    // mm[16] | invc[N] | deg[N] | rp[N] | bsum[256] | erec[2E] |
    // xb[N*128 u16] | hb[N*128 u16] | wt1[9*128*128 u16] | wt2[9*64*128 u16] |
    // proj[N*8*128 u16]  (layer2 aliases same buffer, N*8*64) |
    // aggh[N*128 f32] | agg2[N*64 f32]          total ~172 MB
    int* base = (int*)d_ws;
    float* mm    = (float*)base;
    float* invc  = (float*)(base + 16);
    int*   deg   = base + 16 + N;
    int*   rp    = deg + N;
    int*   bsum  = rp + N;
    int2*  erec  = (int2*)(bsum + 256);
    unsigned short* xb   = (unsigned short*)(bsum + 256 + 2 * E);
    unsigned short* hb   = xb + (size_t)N * 128;
    unsigned short* wt1  = hb + (size_t)N * 128;
    unsigned short* wt2  = wt1 + 9 * 128 * 128;
    unsigned short* proj = wt2 + 9 * 64 * 128;            // N*8*128 u16
    float* aggh = (float*)(proj + (size_t)N * 8 * 128);
    float* agg2 = aggh + (size_t)N * 128;

    const int TB = 256;
    int blocksE = (E + TB - 1) / TB;
    int blocksN = (N + TB - 1) / TB;
    int nb = (N + 1023) / 1024;

    // ---- setup ----
    init_mm<<<1, 64, 0, stream>>>(mm);
    hipMemsetAsync(deg, 0, (size_t)N * sizeof(int), stream);
    count_minmax<<<512, TB, 0, stream>>>(ew, dstp, deg, mm, E);
    long x4 = (long)N * 128 / 4;
    convert_bf16<<<(int)((x4 + TB - 1) / TB), TB, 0, stream>>>(x, xb, x4);
    int wt1n = 9 * 128 * 128, wt2n = 9 * 64 * 128;
    conv_wt<<<(wt1n + TB - 1) / TB, TB, 0, stream>>>(W1, root1, wt1, F_DIM, H_DIM);
    conv_wt<<<(wt2n + TB - 1) / TB, TB, 0, stream>>>(W2, root2, wt2, H_DIM, O_DIM);
    scan1_kernel<<<nb, TB, 0, stream>>>(deg, rp, bsum, invc, N);
    scan2_kernel<<<1, TB, 0, stream>>>(bsum, nb);
    scan3_kernel<<<blocksN, TB, 0, stream>>>(rp, bsum, N);
    fill_kernel<<<blocksE, TB, 0, stream>>>(srcp, dstp, et, ew, mm, rp, erec, E);

    int gB = (N + 63) / 64;
    // ---- layer 1: F=128 -> H=128, relu ----
    gemm_proj<H_DIM><<<gB, TB, 0, stream>>>(xb, wt1, proj, N);
    int gat1 = (int)(((long)N * 16 + TB - 1) / TB);
    gather_all<H_DIM><<<gat1, TB, 0, stream>>>(rp, erec, proj, aggh, N);
    gemm_fin<H_DIM, true, true><<<gB, TB, 0, stream>>>(
        xb, wt1 + (size_t)8 * 128 * 128, aggh, invc, bias1, hb, nullptr, N);

    // ---- layer 2: H=128 -> O=64, no relu ----
    gemm_proj<O_DIM><<<gB, TB, 0, stream>>>(hb, wt2, proj, N);
    int gat2 = (int)(((long)N * 8 + TB - 1) / TB);
    gather_all<O_DIM><<<gat2, TB, 0, stream>>>(rp, erec, proj, agg2, N);
    gemm_fin<O_DIM, false, false><<<gB, TB, 0, stream>>>(
        hb, wt2 + (size_t)8 * 64 * 128, agg2, invc, bias2, nullptr, (float*)d_out, N);
}